// Round 1
// baseline (65.239 us; speedup 1.0000x reference)
//
#include <hip/hip_runtime.h>

constexpr int RADIUS   = 4;
constexpr int MAX_DISP = 192;
constexpr int B  = 2;
constexpr int H  = 256;
constexpr int W  = 512;
constexpr int Hc = H - 2 * RADIUS;   // 248
constexpr int Wc = W - 2 * RADIUS;   // 504

constexpr int BLOCK     = 256;
constexpr int ROWSETS   = B * Hc;        // 496 output rows
constexpr int PRODUCERS = 2 * ROWSETS;   // 992 half-window blocks (A: rows 0-4, B: rows 5-8)
constexpr int TX        = 4;
constexpr int TPR       = Wc / TX;       // 126 census threads per image per block

// Valid packed partial: cost<<32 | cnt. Per half-block cost <= 252*44 = 11088 (<2^16),
// cnt <= 252 (<2^16). d_ws is poisoned 0xAAAA... before every call -> poison fails mask.
constexpr unsigned long long INVALID_MASK = 0xFFFF0000FFFF0000ull;

// ---------------------------------------------------------------------------
// Census bits for window rows [R0, R1). Bit index = (r-R0)*9 + j, unique per
// half, < 45 -> fits one u64. Center hole (r==4,j==4) left as a 0-bit in both
// left and right words: XOR/popcount are unaffected. Hamming distance over the
// full 80 bits is bitwise-separable, so the two half-blocks' costs just add.
// ---------------------------------------------------------------------------
template<int R0, int R1>
__device__ __forceinline__ void
census_bits(const float* __restrict__ base, const float ctr[TX],
            unsigned long long cw[TX]) {
    #pragma unroll
    for (int r = R0; r < R1; ++r) {
        const float4* p = (const float4*)(base + r * W);
        const float4 a = p[0], m = p[1], cc = p[2];     // 3 coalesced 16B loads
        const float f[12] = { a.x,a.y,a.z,a.w, m.x,m.y,m.z,m.w,
                              cc.x,cc.y,cc.z,cc.w };
        #pragma unroll
        for (int j = 0; j < 9; ++j) {
            if (r == 4 && j == 4) continue;             // skip center
            const int bit = (r - R0) * 9 + j;           // compile-time
            #pragma unroll
            for (int q = 0; q < TX; ++q) {
                const unsigned long long tb = (f[q + j] > ctr[q]) ? 1ull : 0ull;
                cw[q] |= tb << bit;
            }
        }
    }
}

// ---------------------------------------------------------------------------
// One half-window partial per block (valid on tid 0 only).
// waves 0-1: right census -> LDS rbuf (u64); waves 2-3: left census -> regs;
// sync; left threads gather rbuf[x+d], popcount, block-reduce.
// cnt (valid-pixel count) contributed by half==0 blocks only.
// ---------------------------------------------------------------------------
__device__ __forceinline__ unsigned long long
half_partial(const float* __restrict__ left,
             const float* __restrict__ right,
             const float* __restrict__ disp,
             unsigned long long* rbuf, uint2* red, int bid) {
    const int row  = bid >> 1;               // output row 0..495
    const int half = bid & 1;                // 0: window rows 0..4, 1: rows 5..8
    const int b    = row / Hc;
    const int y    = row % Hc;               // window top row; center = y+4
    const int tid  = threadIdx.x;
    const bool isRight = (tid < 128);
    const int t    = tid & 127;
    const int x0   = t * TX;
    const bool active = (t < TPR);

    // Early independent disp load (hides under census compute).
    float dv[TX] = {0.f, 0.f, 0.f, 0.f};
    if (!isRight && active) {
        const float4 d4 = *(const float4*)(disp + ((size_t)b * H + y + RADIUS) * W
                                                + x0 + RADIUS);   // 16B aligned
        dv[0] = d4.x; dv[1] = d4.y; dv[2] = d4.z; dv[3] = d4.w;
    }

    unsigned long long cw[TX] = {0ull, 0ull, 0ull, 0ull};
    if (active) {
        const float* img  = isRight ? right : left;               // wave-uniform
        const float* base = img + ((size_t)b * H + y) * W + x0;   // 16B aligned

        const float4 c4 = *(const float4*)(base + 4 * W + 4);     // centers (row 4)
        const float ctr[TX] = { c4.x, c4.y, c4.z, c4.w };

        if (half == 0) census_bits<0, 5>(base, ctr, cw);          // 44 bits
        else           census_bits<5, 9>(base, ctr, cw);          // 36 bits
    }
    if (isRight && active) {
        #pragma unroll
        for (int q = 0; q < TX; ++q) rbuf[x0 + q] = cw[q];
    }
    __syncthreads();

    unsigned int cost = 0, cnt = 0;
    if (!isRight && active) {
        #pragma unroll
        for (int q = 0; q < TX; ++q) {
            if (dv[q] > 0.0f) {
                if (half == 0) ++cnt;       // count each valid pixel exactly once
                const int x = x0 + q;
                const int d = min((int)dv[q], MAX_DISP - 1);
                // out-of-range column: right census vector == 0 in reference
                const unsigned long long r64 = (x + d < Wc) ? rbuf[x + d] : 0ull;
                cost += (unsigned int)__popcll(cw[q] ^ r64);
            }
        }
    }

    #pragma unroll
    for (int off = 32; off > 0; off >>= 1) {
        cost += __shfl_down(cost, off);
        cnt  += __shfl_down(cnt,  off);
    }
    const int wave = tid >> 6;
    if ((tid & 63) == 0) red[wave] = make_uint2(cost, cnt);
    __syncthreads();

    unsigned int c = 0, n = 0;
    if (tid == 0) {
        #pragma unroll
        for (int w = 0; w < BLOCK / 64; ++w) { c += red[w].x; n += red[w].y; }
    }
    return ((unsigned long long)c << 32) | n;   // valid only on tid 0
}

// ---------------------------------------------------------------------------
// Single dispatch, NO cooperative launch (coop launch crashes graph capture),
// NO contended atomics:
//   blocks 0..PRODUCERS-1 : half-window work -> agent-scope store of partial
//   block  PRODUCERS      : spins until partials non-poison, reduces, writes out.
// 993 blocks x 4 waves = 3972 waves -> trivially co-resident (4KB LDS/block).
// ---------------------------------------------------------------------------
__global__ __launch_bounds__(BLOCK)
void fused_single_kernel(const float* __restrict__ left,
                         const float* __restrict__ right,
                         const float* __restrict__ disp,
                         unsigned long long* __restrict__ partials,
                         float* __restrict__ out) {
    __shared__ unsigned long long rbuf[Wc];     // 4032 B
    __shared__ uint2 red[BLOCK / 64];

    const int bid = blockIdx.x;
    if (bid < PRODUCERS) {
        const unsigned long long packed =
            half_partial(left, right, disp, rbuf, red, bid);
        if (threadIdx.x == 0)
            __hip_atomic_store(&partials[bid], packed,
                               __ATOMIC_RELAXED, __HIP_MEMORY_SCOPE_AGENT);
        return;
    }

    // --- reducer block ---
    unsigned int c = 0, n = 0;
    for (int i = threadIdx.x; i < PRODUCERS; i += BLOCK) {
        unsigned long long p;
        for (;;) {
            p = __hip_atomic_load(&partials[i], __ATOMIC_RELAXED,
                                  __HIP_MEMORY_SCOPE_AGENT);
            if ((p & INVALID_MASK) == 0ull) break;   // poison 0xAA.. fails this
            __builtin_amdgcn_s_sleep(1);
        }
        c += (unsigned int)(p >> 32);
        n += (unsigned int)(p & 0xffffffffu);
    }
    #pragma unroll
    for (int off = 32; off > 0; off >>= 1) {
        c += __shfl_down(c, off);
        n += __shfl_down(n, off);
    }
    const int wave = threadIdx.x >> 6;
    if ((threadIdx.x & 63) == 0) red[wave] = make_uint2(c, n);
    __syncthreads();
    if (threadIdx.x == 0) {
        unsigned int tc = 0, tn = 0;
        #pragma unroll
        for (int w = 0; w < BLOCK / 64; ++w) { tc += red[w].x; tn += red[w].y; }
        out[0] = (float)tc / ((float)tn + 1e-6f);
    }
}

extern "C" void kernel_launch(void* const* d_in, const int* in_sizes, int n_in,
                              void* d_out, int out_size, void* d_ws, size_t ws_size,
                              hipStream_t stream) {
    const float* left  = (const float*)d_in[0];
    const float* right = (const float*)d_in[1];
    const float* disp  = (const float*)d_in[2];
    float* out = (float*)d_out;
    unsigned long long* partials = (unsigned long long*)d_ws;  // PRODUCERS * 8 B

    fused_single_kernel<<<PRODUCERS + 1, BLOCK, 0, stream>>>(left, right, disp,
                                                             partials, out);
}